// Round 3
// baseline (191.564 us; speedup 1.0000x reference)
//
#include <hip/hip_runtime.h>
#include <hip/hip_cooperative_groups.h>

// S=32 systems, N=512 atoms/system, F=256 features
#define SY 32
#define NA 512
#define FD 256

typedef __attribute__((ext_vector_type(8))) short bf16x8;   // 8 bf16 = 4 VGPRs
typedef __attribute__((ext_vector_type(4))) float f32x4;    // MFMA C/D frag

static __device__ __forceinline__ short f2bf(float x) {
    union { float f; unsigned u; } v; v.f = x;
    unsigned r = v.u + 0x7fffu + ((v.u >> 16) & 1u);   // RNE
    return (short)(r >> 16);
}

// ---------------------------------------------------------------------------
// Kernel 1: charges = features @ W^T + b  -> written into d_out (gbuf).
// fp32 exact path, 64x64 tile, validated in round 2.
// ---------------------------------------------------------------------------
__global__ __launch_bounds__(256) void charges_kernel(
    const float* __restrict__ feat, const float* __restrict__ W,
    const float* __restrict__ b, float* __restrict__ q)
{
    __shared__ float sA[64][65];  // [k][i]
    __shared__ float sB[64][65];  // [k][f]
    const int t  = threadIdx.x;
    const int i0 = blockIdx.x * 64;
    const int f0 = blockIdx.y * 64;
    const int ti = t & 15;
    const int tj = t >> 4;

    float acc[4][4] = {};

    for (int k0 = 0; k0 < FD; k0 += 64) {
        #pragma unroll
        for (int m = 0; m < 4; ++m) {
            int lin = t + 256 * m;
            int row = lin >> 4;
            int kc  = (lin & 15) << 2;
            float4 v = *(const float4*)&feat[(size_t)(i0 + row) * FD + k0 + kc];
            sA[kc + 0][row] = v.x; sA[kc + 1][row] = v.y;
            sA[kc + 2][row] = v.z; sA[kc + 3][row] = v.w;
        }
        #pragma unroll
        for (int m = 0; m < 4; ++m) {
            int lin = t + 256 * m;
            int fi  = lin >> 4;
            int kc  = (lin & 15) << 2;
            float4 v = *(const float4*)&W[(size_t)(f0 + fi) * FD + k0 + kc];
            sB[kc + 0][fi] = v.x; sB[kc + 1][fi] = v.y;
            sB[kc + 2][fi] = v.z; sB[kc + 3][fi] = v.w;
        }
        __syncthreads();

        #pragma unroll 8
        for (int k = 0; k < 64; ++k) {
            float av[4], bv[4];
            #pragma unroll
            for (int d = 0; d < 4; ++d) av[d] = sA[k][4 * ti + d];
            #pragma unroll
            for (int d = 0; d < 4; ++d) bv[d] = sB[k][4 * tj + d];
            #pragma unroll
            for (int a = 0; a < 4; ++a)
                #pragma unroll
                for (int c = 0; c < 4; ++c)
                    acc[a][c] += av[a] * bv[c];
        }
        __syncthreads();
    }

    float4 bv = *(const float4*)&b[f0 + 4 * tj];
    #pragma unroll
    for (int a = 0; a < 4; ++a) {
        float4 o;
        o.x = acc[a][0] + bv.x; o.y = acc[a][1] + bv.y;
        o.z = acc[a][2] + bv.z; o.w = acc[a][3] + bv.w;
        *(float4*)&q[(size_t)(i0 + 4 * ti + a) * FD + f0 + 4 * tj] = o;
    }
}

// ---------------------------------------------------------------------------
// Kernel 2 (cooperative): V = 0.5 * v @ q via bf16 MFMA, then (after grid
// sync) in-place out = V * q. gbuf (= d_out) holds q on entry, out on exit.
// Block = (i-chunk 0..7, system 0..31). 256 threads = 4 waves.
//   wave w: f-tiles 4w..4w+3, i-tiles 0..3 -> 16 acc frags (64 VGPRs).
// LDS: q staged bf16 transposed [f][j] (pitch 40, +stagger), v bf16 [i][j].
// ---------------------------------------------------------------------------
__global__ __launch_bounds__(256) void lr_coop(
    const float* __restrict__ pos, float* __restrict__ gbuf)
{
    __shared__ float px[NA], py[NA], pz[NA];
    __shared__ __attribute__((aligned(16))) short svb[64 * 40];  // v bf16 [i][j-blk]
    __shared__ __attribute__((aligned(16))) short sqb[FD * 40];  // q bf16 [f][j-blk]

    const int ic = blockIdx.x;          // i-chunk 0..7
    const int s  = blockIdx.y;          // system 0..31
    const int i0 = ic * 64;
    const int t  = threadIdx.x;
    const int w    = t >> 6;            // wave 0..3
    const int lane = t & 63;
    const int n16  = lane & 15;
    const int quad = lane >> 4;

    for (int m = t; m < NA; m += 256) {
        const float* p = &pos[((size_t)s * NA + m) * 3];
        px[m] = p[0]; py[m] = p[1]; pz[m] = p[2];
    }

    f32x4 acc[4][4];
    #pragma unroll
    for (int a = 0; a < 4; ++a)
        #pragma unroll
        for (int c = 0; c < 4; ++c) acc[a][c] = (f32x4)0.0f;

    __syncthreads();

    const int fq  = t >> 2;   // f-quad 0..63 (q staging)
    const int jb  = t & 3;    // j-block 0..3 (q staging)
    const int iv  = t & 63;   // i (v staging)
    const int jbv = t >> 6;   // j-block (v staging)
    const int gi  = i0 + iv;

    for (int j0 = 0; j0 < NA; j0 += 32) {
        // ---- stage q -> sqb: bf16, transposed to [f][j] ----
        bf16x8 rows[4];
        #pragma unroll
        for (int m = 0; m < 8; ++m) {
            int j = 8 * jb + m;
            float4 v4 = *(const float4*)&gbuf[((size_t)s * NA + j0 + j) * FD + 4 * fq];
            rows[0][m] = f2bf(v4.x);
            rows[1][m] = f2bf(v4.y);
            rows[2][m] = f2bf(v4.z);
            rows[3][m] = f2bf(v4.w);
        }
        #pragma unroll
        for (int d = 0; d < 4; ++d) {
            int f = 4 * fq + d;
            int phys = (jb + (f >> 3)) & 3;   // stagger vs bank aliasing
            *(bf16x8*)&sqb[f * 40 + phys * 8] = rows[d];
        }
        // ---- v tile: 64 i x 32 j, bf16 (0.5 energy factor folded in) ----
        {
            bf16x8 vrow;
            #pragma unroll
            for (int jj = 0; jj < 8; ++jj) {
                int gj = j0 + 8 * jbv + jj;
                float dx = px[gi] - px[gj];
                float dy = py[gi] - py[gj];
                float dz = pz[gi] - pz[gj];
                float dd = sqrtf(dx * dx + dy * dy + dz * dz);
                // 1 - fcut = 0.5*(1 - cos(pi*d/5)) for d<5, else 1
                float om = (dd < 5.0f) ? 0.5f * (1.0f - __cosf(dd * 0.62831853071795f))
                                       : 1.0f;
                float vv = (gi != gj) ? (0.5f * om / dd) : 0.0f;
                vrow[jj] = f2bf(vv);
            }
            int phys = (jbv + (iv >> 3)) & 3;
            *(bf16x8*)&svb[iv * 40 + phys * 8] = vrow;
        }
        __syncthreads();

        // ---- MFMA: 4 a-frags + 4 b-frags -> 16 mfma per wave ----
        bf16x8 af[4], bfr[4];
        #pragma unroll
        for (int it = 0; it < 4; ++it) {
            int i = 16 * it + n16;
            int phys = (quad + (i >> 3)) & 3;
            af[it] = *(const bf16x8*)&svb[i * 40 + phys * 8];
        }
        #pragma unroll
        for (int fb = 0; fb < 4; ++fb) {
            int f = 16 * (4 * w + fb) + n16;
            int phys = (quad + (f >> 3)) & 3;
            bfr[fb] = *(const bf16x8*)&sqb[f * 40 + phys * 8];
        }
        #pragma unroll
        for (int it = 0; it < 4; ++it)
            #pragma unroll
            for (int fb = 0; fb < 4; ++fb)
                acc[it][fb] = __builtin_amdgcn_mfma_f32_16x16x32_bf16(
                    af[it], bfr[fb], acc[it][fb], 0, 0, 0);
        __syncthreads();
    }

    // all blocks finished READING q from gbuf; now safe to overwrite in place
    cooperative_groups::this_grid().sync();

    // epilogue: out = V * q, element-wise, each address owned by one thread.
    // C/D layout: col f = lane&15 (+16*tile), row i = quad*4 + reg (+16*tile)
    #pragma unroll
    for (int it = 0; it < 4; ++it)
        #pragma unroll
        for (int fb = 0; fb < 4; ++fb)
            #pragma unroll
            for (int r = 0; r < 4; ++r) {
                int i = i0 + 16 * it + 4 * quad + r;
                int f = 16 * (4 * w + fb) + n16;
                size_t a = ((size_t)s * NA + i) * FD + f;
                gbuf[a] = acc[it][fb][r] * gbuf[a];
            }
}

extern "C" void kernel_launch(void* const* d_in, const int* in_sizes, int n_in,
                              void* d_out, int out_size, void* d_ws, size_t ws_size,
                              hipStream_t stream) {
    const float* positions = (const float*)d_in[0];  // [32,512,3]
    const float* features  = (const float*)d_in[1];  // [16384,256]
    const float* W         = (const float*)d_in[2];  // [256,256]
    const float* b         = (const float*)d_in[3];  // [256]
    float* gbuf = (float*)d_out;                     // q, then out (in-place)
    (void)d_ws; (void)ws_size;                       // workspace unused (OOB fix)

    charges_kernel<<<dim3(256, 4), 256, 0, stream>>>(features, W, b, gbuf);

    void* args[] = {(void*)&positions, (void*)&gbuf};
    hipLaunchCooperativeKernel((void*)lr_coop, dim3(8, SY), dim3(256),
                               args, 0, stream);
}

// Round 4
// 150.440 us; speedup vs baseline: 1.2734x; 1.2734x over previous
//
#include <hip/hip_runtime.h>
#include <hip/hip_cooperative_groups.h>

// S=32 systems, N=512 atoms/system, F=256 features
#define SY 32
#define NA 512
#define FD 256

typedef __attribute__((ext_vector_type(8))) short bf16x8;   // 8 bf16 = 4 VGPRs
typedef __attribute__((ext_vector_type(4))) short bf16x4;   // 4 bf16 = 8 B
typedef __attribute__((ext_vector_type(4))) float f32x4;    // MFMA C/D frag

static __device__ __forceinline__ short f2bf(float x) {
    union { float f; unsigned u; } v; v.f = x;
    unsigned r = v.u + 0x7fffu + ((v.u >> 16) & 1u);   // RNE
    return (short)(r >> 16);
}

// ---------------------------------------------------------------------------
// Kernel 1: charges = features @ W^T + b via bf16 MFMA (fp32 accum).
// Block: 64 i-rows x 256 f (full F). 4 waves; wave w owns f in [64w,64w+64).
// K staged in chunks of 64 (bf16, [row][k] pitch 72 ushort, 16B-aligned).
// A-frag: lane = A[i=16it+n16][k=quad*8+j]; B-frag: B[f=...][k=quad*8+j];
// C/D: col f = lane&15, row i = quad*4 + r  (layout validated in round 3).
// ---------------------------------------------------------------------------
__global__ __launch_bounds__(256) void charges_mfma(
    const float* __restrict__ feat, const float* __restrict__ W,
    const float* __restrict__ b, float* __restrict__ q)
{
    __shared__ __attribute__((aligned(16))) short sA[64 * 72];   //  9.2 KB
    __shared__ __attribute__((aligned(16))) short sB[256 * 72];  // 36.9 KB
    const int t    = threadIdx.x;
    const int i0   = blockIdx.x * 64;
    const int w    = t >> 6;
    const int lane = t & 63;
    const int n16  = lane & 15;
    const int quad = lane >> 4;

    f32x4 acc[4][4];
    #pragma unroll
    for (int a = 0; a < 4; ++a)
        #pragma unroll
        for (int c = 0; c < 4; ++c) acc[a][c] = (f32x4)0.0f;

    for (int k0 = 0; k0 < FD; k0 += 64) {
        // stage feat tile: 64 i x 64 k  (4 float4/thread)
        #pragma unroll
        for (int m = 0; m < 4; ++m) {
            int lin = t + 256 * m;
            int i = lin >> 4, kq = lin & 15;
            float4 v = *(const float4*)&feat[(size_t)(i0 + i) * FD + k0 + 4 * kq];
            bf16x4 p; p[0] = f2bf(v.x); p[1] = f2bf(v.y);
                      p[2] = f2bf(v.z); p[3] = f2bf(v.w);
            *(bf16x4*)&sA[i * 72 + 4 * kq] = p;
        }
        // stage W tile: 256 f x 64 k  (16 float4/thread; L2-resident)
        #pragma unroll
        for (int m = 0; m < 16; ++m) {
            int lin = t + 256 * m;
            int f = lin >> 4, kq = lin & 15;
            float4 v = *(const float4*)&W[(size_t)f * FD + k0 + 4 * kq];
            bf16x4 p; p[0] = f2bf(v.x); p[1] = f2bf(v.y);
                      p[2] = f2bf(v.z); p[3] = f2bf(v.w);
            *(bf16x4*)&sB[f * 72 + 4 * kq] = p;
        }
        __syncthreads();

        #pragma unroll
        for (int ks = 0; ks < 64; ks += 32) {
            bf16x8 af[4], bfr[4];
            #pragma unroll
            for (int it = 0; it < 4; ++it)
                af[it] = *(const bf16x8*)&sA[(16 * it + n16) * 72 + ks + quad * 8];
            #pragma unroll
            for (int fb = 0; fb < 4; ++fb)
                bfr[fb] = *(const bf16x8*)&sB[(64 * w + 16 * fb + n16) * 72 + ks + quad * 8];
            #pragma unroll
            for (int it = 0; it < 4; ++it)
                #pragma unroll
                for (int fb = 0; fb < 4; ++fb)
                    acc[it][fb] = __builtin_amdgcn_mfma_f32_16x16x32_bf16(
                        af[it], bfr[fb], acc[it][fb], 0, 0, 0);
        }
        __syncthreads();
    }

    float bias[4];
    #pragma unroll
    for (int fb = 0; fb < 4; ++fb) bias[fb] = b[64 * w + 16 * fb + n16];
    #pragma unroll
    for (int it = 0; it < 4; ++it)
        #pragma unroll
        for (int fb = 0; fb < 4; ++fb)
            #pragma unroll
            for (int r = 0; r < 4; ++r) {
                int i = i0 + 16 * it + 4 * quad + r;
                int f = 64 * w + 16 * fb + n16;
                q[(size_t)i * FD + f] = acc[it][fb][r] + bias[fb];
            }
}

// ---------------------------------------------------------------------------
// Kernel 2 (cooperative): V = 0.5 * v @ q via bf16 MFMA, then grid.sync,
// then in-place out = V * q. gbuf (= d_out) holds q on entry, out on exit.
// 1-D grid 256: s = b & 31, ic = b >> 5  -> all 8 i-chunk blocks of a system
// share an XCD (b mod 8 = s mod 8) so q[s] re-reads hit that XCD's 4MB L2.
// j-loop: q prefetched one step ahead into regs; pair-potential VALU overlaps
// load latency; staged bf16 transposed [f][j] (pitch 40 + stagger, validated).
// ---------------------------------------------------------------------------
__global__ __launch_bounds__(256) void lr_coop(
    const float* __restrict__ pos, float* __restrict__ gbuf)
{
    __shared__ float px[NA], py[NA], pz[NA];
    __shared__ __attribute__((aligned(16))) short svb[64 * 40];  // v bf16 [i][j-blk]
    __shared__ __attribute__((aligned(16))) short sqb[FD * 40];  // q bf16 [f][j-blk]

    const int blk = blockIdx.x;
    const int s   = blk & 31;           // system (XCD-local swizzle)
    const int i0  = (blk >> 5) * 64;    // i-chunk
    const int t   = threadIdx.x;
    const int w    = t >> 6;            // wave 0..3
    const int lane = t & 63;
    const int n16  = lane & 15;
    const int quad = lane >> 4;

    for (int m = t; m < NA; m += 256) {
        const float* p = &pos[((size_t)s * NA + m) * 3];
        px[m] = p[0]; py[m] = p[1]; pz[m] = p[2];
    }

    f32x4 acc[4][4];
    #pragma unroll
    for (int a = 0; a < 4; ++a)
        #pragma unroll
        for (int c = 0; c < 4; ++c) acc[a][c] = (f32x4)0.0f;

    __syncthreads();

    const int fq  = t >> 2;   // f-quad 0..63 (q staging)
    const int jb  = t & 3;    // j-block 0..3 (q staging)
    const int iv  = t & 63;   // i (v staging)
    const int jbv = t >> 6;   // j-block (v staging)
    const int gi  = i0 + iv;

    // prefetch q tile for j0=0
    float4 rq[8];
    #pragma unroll
    for (int m = 0; m < 8; ++m)
        rq[m] = *(const float4*)&gbuf[((size_t)s * NA + 8 * jb + m) * FD + 4 * fq];

    for (int j0 = 0; j0 < NA; j0 += 32) {
        // ---- pair-potential tile (independent of rq -> overlaps load latency)
        bf16x8 vrow;
        #pragma unroll
        for (int jj = 0; jj < 8; ++jj) {
            int gj = j0 + 8 * jbv + jj;
            float dx = px[gi] - px[gj];
            float dy = py[gi] - py[gj];
            float dz = pz[gi] - pz[gj];
            float dd = sqrtf(dx * dx + dy * dy + dz * dz);
            // 1 - fcut = 0.5*(1 - cos(pi*d/5)) for d<5, else 1; 0.5 energy factor
            float om = (dd < 5.0f) ? 0.5f * (1.0f - __cosf(dd * 0.62831853071795f))
                                   : 1.0f;
            float vv = (gi != gj) ? (0.5f * om * __builtin_amdgcn_rcpf(dd)) : 0.0f;
            vrow[jj] = f2bf(vv);
        }
        // ---- convert prefetched q -> sqb (bf16, transposed [f][j])
        bf16x8 rows[4];
        #pragma unroll
        for (int m = 0; m < 8; ++m) {
            rows[0][m] = f2bf(rq[m].x);
            rows[1][m] = f2bf(rq[m].y);
            rows[2][m] = f2bf(rq[m].z);
            rows[3][m] = f2bf(rq[m].w);
        }
        #pragma unroll
        for (int d = 0; d < 4; ++d) {
            int f = 4 * fq + d;
            int phys = (jb + (f >> 3)) & 3;   // stagger vs bank aliasing
            *(bf16x8*)&sqb[f * 40 + phys * 8] = rows[d];
        }
        {
            int phys = (jbv + (iv >> 3)) & 3;
            *(bf16x8*)&svb[iv * 40 + phys * 8] = vrow;
        }
        // ---- issue next j-step's q loads (overlap MFMA + next pair compute)
        {
            int jn = (j0 + 32) & (NA - 1);
            #pragma unroll
            for (int m = 0; m < 8; ++m)
                rq[m] = *(const float4*)&gbuf[((size_t)s * NA + jn + 8 * jb + m) * FD + 4 * fq];
        }
        __syncthreads();

        // ---- MFMA: 4 a-frags x 4 b-frags -> 16 mfma per wave
        bf16x8 af[4], bfr[4];
        #pragma unroll
        for (int it = 0; it < 4; ++it) {
            int i = 16 * it + n16;
            int phys = (quad + (i >> 3)) & 3;
            af[it] = *(const bf16x8*)&svb[i * 40 + phys * 8];
        }
        #pragma unroll
        for (int fb = 0; fb < 4; ++fb) {
            int f = 16 * (4 * w + fb) + n16;
            int phys = (quad + (f >> 3)) & 3;
            bfr[fb] = *(const bf16x8*)&sqb[f * 40 + phys * 8];
        }
        #pragma unroll
        for (int it = 0; it < 4; ++it)
            #pragma unroll
            for (int fb = 0; fb < 4; ++fb)
                acc[it][fb] = __builtin_amdgcn_mfma_f32_16x16x32_bf16(
                    af[it], bfr[fb], acc[it][fb], 0, 0, 0);
        __syncthreads();
    }

    // all blocks finished READING q from gbuf; safe to overwrite in place
    cooperative_groups::this_grid().sync();

    // epilogue: out = V * q (each address owned by exactly one thread)
    #pragma unroll
    for (int it = 0; it < 4; ++it)
        #pragma unroll
        for (int fb = 0; fb < 4; ++fb)
            #pragma unroll
            for (int r = 0; r < 4; ++r) {
                int i = i0 + 16 * it + 4 * quad + r;
                int f = 16 * (4 * w + fb) + n16;
                size_t a = ((size_t)s * NA + i) * FD + f;
                gbuf[a] = acc[it][fb][r] * gbuf[a];
            }
}

extern "C" void kernel_launch(void* const* d_in, const int* in_sizes, int n_in,
                              void* d_out, int out_size, void* d_ws, size_t ws_size,
                              hipStream_t stream) {
    const float* positions = (const float*)d_in[0];  // [32,512,3]
    const float* features  = (const float*)d_in[1];  // [16384,256]
    const float* W         = (const float*)d_in[2];  // [256,256]
    const float* b         = (const float*)d_in[3];  // [256]
    float* gbuf = (float*)d_out;                     // q, then out (in-place)
    (void)d_ws; (void)ws_size;                       // workspace unused

    charges_mfma<<<dim3(256), 256, 0, stream>>>(features, W, b, gbuf);

    void* args[] = {(void*)&positions, (void*)&gbuf};
    hipLaunchCooperativeKernel((void*)lr_coop, dim3(256), dim3(256),
                               args, 0, stream);
}

// Round 5
// 135.500 us; speedup vs baseline: 1.4138x; 1.1103x over previous
//
#include <hip/hip_runtime.h>
#include <hip/hip_cooperative_groups.h>

// S=32 systems, N=512 atoms/system, F=256 features
#define SY 32
#define NA 512
#define FD 256

typedef __attribute__((ext_vector_type(8))) short bf16x8;   // 8 bf16 = 4 VGPRs
typedef __attribute__((ext_vector_type(4))) short bf16x4;   // 4 bf16 = 8 B
typedef __attribute__((ext_vector_type(4))) float f32x4;    // MFMA C/D frag

static __device__ __forceinline__ short f2bf(float x) {
    union { float f; unsigned u; } v; v.f = x;
    unsigned r = v.u + 0x7fffu + ((v.u >> 16) & 1u);   // RNE
    return (short)(r >> 16);
}

// ---------------------------------------------------------------------------
// Kernel 1: charges = features @ W^T + b via bf16 MFMA (fp32 accum).
// Writes q fp32 -> gbuf (d_out) and, if qT != nullptr, bf16 transposed
// qT[s][f][j] -> workspace (for the non-coop lr_fast path).
// Structure validated in round 4.
// ---------------------------------------------------------------------------
__global__ __launch_bounds__(256) void charges_mfma(
    const float* __restrict__ feat, const float* __restrict__ W,
    const float* __restrict__ b, float* __restrict__ q,
    short* __restrict__ qT)
{
    __shared__ __attribute__((aligned(16))) short sA[64 * 72];   //  9.2 KB
    __shared__ __attribute__((aligned(16))) short sB[256 * 72];  // 36.9 KB
    const int t    = threadIdx.x;
    const int i0   = blockIdx.x * 64;
    const int w    = t >> 6;
    const int lane = t & 63;
    const int n16  = lane & 15;
    const int quad = lane >> 4;

    f32x4 acc[4][4];
    #pragma unroll
    for (int a = 0; a < 4; ++a)
        #pragma unroll
        for (int c = 0; c < 4; ++c) acc[a][c] = (f32x4)0.0f;

    for (int k0 = 0; k0 < FD; k0 += 64) {
        #pragma unroll
        for (int m = 0; m < 4; ++m) {
            int lin = t + 256 * m;
            int i = lin >> 4, kq = lin & 15;
            float4 v = *(const float4*)&feat[(size_t)(i0 + i) * FD + k0 + 4 * kq];
            bf16x4 p; p[0] = f2bf(v.x); p[1] = f2bf(v.y);
                      p[2] = f2bf(v.z); p[3] = f2bf(v.w);
            *(bf16x4*)&sA[i * 72 + 4 * kq] = p;
        }
        #pragma unroll
        for (int m = 0; m < 16; ++m) {
            int lin = t + 256 * m;
            int f = lin >> 4, kq = lin & 15;
            float4 v = *(const float4*)&W[(size_t)f * FD + k0 + 4 * kq];
            bf16x4 p; p[0] = f2bf(v.x); p[1] = f2bf(v.y);
                      p[2] = f2bf(v.z); p[3] = f2bf(v.w);
            *(bf16x4*)&sB[f * 72 + 4 * kq] = p;
        }
        __syncthreads();

        #pragma unroll
        for (int ks = 0; ks < 64; ks += 32) {
            bf16x8 af[4], bfr[4];
            #pragma unroll
            for (int it = 0; it < 4; ++it)
                af[it] = *(const bf16x8*)&sA[(16 * it + n16) * 72 + ks + quad * 8];
            #pragma unroll
            for (int fb = 0; fb < 4; ++fb)
                bfr[fb] = *(const bf16x8*)&sB[(64 * w + 16 * fb + n16) * 72 + ks + quad * 8];
            #pragma unroll
            for (int it = 0; it < 4; ++it)
                #pragma unroll
                for (int fb = 0; fb < 4; ++fb)
                    acc[it][fb] = __builtin_amdgcn_mfma_f32_16x16x32_bf16(
                        af[it], bfr[fb], acc[it][fb], 0, 0, 0);
        }
        __syncthreads();
    }

    float bias[4];
    #pragma unroll
    for (int fb = 0; fb < 4; ++fb) bias[fb] = b[64 * w + 16 * fb + n16];

    #pragma unroll
    for (int it = 0; it < 4; ++it)
        #pragma unroll
        for (int fb = 0; fb < 4; ++fb)
            #pragma unroll
            for (int r = 0; r < 4; ++r) {
                int i = i0 + 16 * it + 4 * quad + r;
                int f = 64 * w + 16 * fb + n16;
                q[(size_t)i * FD + f] = acc[it][fb][r] + bias[fb];
            }

    if (qT) {   // bf16 transposed copy: qT[s][f][j], j = i % 512
        short* qTs = qT + ((size_t)(i0 >> 9)) * FD * NA;
        const int ilb = (i0 & 511) + 4 * quad;
        #pragma unroll
        for (int it = 0; it < 4; ++it)
            #pragma unroll
            for (int fb = 0; fb < 4; ++fb) {
                bf16x4 p;
                #pragma unroll
                for (int r = 0; r < 4; ++r) p[r] = f2bf(acc[it][fb][r] + bias[fb]);
                int f = 64 * w + 16 * fb + n16;
                *(bf16x4*)&qTs[(size_t)f * NA + ilb + 16 * it] = p;
            }
    }
}

// ---------------------------------------------------------------------------
// Kernel 2 FAST (non-coop): V = 0.5 * v @ q (bf16 MFMA), out = V * q.
// All cross-row q reads come from qT (ws); d_out rows are each written only
// by their owner block -> no grid sync needed.
// Grid 512 = (s = b&31 [XCD-local], ichunk = b>>5 of 32 rows); 2 blocks/CU.
// LDS chunk swizzle: 16B chunk c of row x stored at slot (c+x)&7 ->
// conflict-free staging, 2-way (free) fragment reads.
// ---------------------------------------------------------------------------
__global__ __launch_bounds__(256) void lr_fast(
    const float* __restrict__ pos, float* __restrict__ gbuf,
    const short* __restrict__ qT)
{
    __shared__ float px[NA], py[NA], pz[NA];
    __shared__ __attribute__((aligned(16))) short sqb[FD * 64];  // 32 KB [f][64j swz]
    __shared__ __attribute__((aligned(16))) short svb[32 * 64];  //  4 KB [i][64j swz]

    const int blk = blockIdx.x;
    const int s   = blk & 31;
    const int i0  = (blk >> 5) * 32;
    const int t   = threadIdx.x;
    const int w    = t >> 6;
    const int lane = t & 63;
    const int n16  = lane & 15;
    const int quad = lane >> 4;

    for (int m = t; m < NA; m += 256) {
        const float* p = &pos[((size_t)s * NA + m) * 3];
        px[m] = p[0]; py[m] = p[1]; pz[m] = p[2];
    }

    f32x4 acc[2][4];
    #pragma unroll
    for (int a = 0; a < 2; ++a)
        #pragma unroll
        for (int c = 0; c < 4; ++c) acc[a][c] = (f32x4)0.0f;

    const short* qTs = qT + (size_t)s * FD * NA;
    const int pi = t & 31;        // pair-tile i
    const int pc = t >> 5;        // pair-tile j-chunk 0..7
    const int gi = i0 + pi;

    __syncthreads();
    const float xi = px[gi], yi = py[gi], zi = pz[gi];

    for (int j0 = 0; j0 < NA; j0 += 64) {
        // ---- stage q tile: 256f x 64j bf16, 8 x 16B chunks per thread ----
        #pragma unroll
        for (int n = 0; n < 8; ++n) {
            int S  = n * 256 + t;        // 0..2047
            int f  = S >> 3;
            int cs = S & 7;              // LDS slot
            int c  = (cs - f) & 7;       // source chunk
            uint4 v = *(const uint4*)&qTs[(size_t)f * NA + j0 + c * 8];
            *(uint4*)&sqb[f * 64 + cs * 8] = v;
        }
        // ---- v tile: 32i x 64j ----
        bf16x8 vrow;
        #pragma unroll
        for (int jj = 0; jj < 8; ++jj) {
            int gj = j0 + pc * 8 + jj;
            float dx = xi - px[gj];
            float dy = yi - py[gj];
            float dz = zi - pz[gj];
            float r2 = dx * dx + dy * dy + dz * dz;
            float inv = __builtin_amdgcn_rsqf(r2);
            float dd  = r2 * inv;
            // 1 - fcut = sin^2(pi*d/10) for d<5, else 1; 0.5 energy factor
            float sn = __sinf(dd * 0.31415926535f);
            float om = (dd < 5.0f) ? sn * sn : 1.0f;
            float vv = (gi != gj) ? 0.5f * om * inv : 0.0f;
            vrow[jj] = f2bf(vv);
        }
        *(bf16x8*)&svb[pi * 64 + (((pc + pi) & 7) * 8)] = vrow;
        __syncthreads();

        // ---- fragments + MFMA: 2 it x 4 fb x 2 kh = 16 mfma / wave ----
        bf16x8 af[2][2], bfr[2][4];
        #pragma unroll
        for (int it = 0; it < 2; ++it)
            #pragma unroll
            for (int kh = 0; kh < 2; ++kh) {
                int i = 16 * it + n16;
                int c = kh * 4 + quad;
                af[it][kh] = *(const bf16x8*)&svb[i * 64 + (((c + i) & 7) * 8)];
            }
        #pragma unroll
        for (int fb = 0; fb < 4; ++fb)
            #pragma unroll
            for (int kh = 0; kh < 2; ++kh) {
                int f = 64 * w + 16 * fb + n16;
                int c = kh * 4 + quad;
                bfr[kh][fb] = *(const bf16x8*)&sqb[f * 64 + (((c + f) & 7) * 8)];
            }
        #pragma unroll
        for (int kh = 0; kh < 2; ++kh)
            #pragma unroll
            for (int it = 0; it < 2; ++it)
                #pragma unroll
                for (int fb = 0; fb < 4; ++fb)
                    acc[it][fb] = __builtin_amdgcn_mfma_f32_16x16x32_bf16(
                        af[it][kh], bfr[kh][fb], acc[it][fb], 0, 0, 0);
        __syncthreads();
    }

    // epilogue: out = V * q (fp32 q from gbuf; only this block writes its rows)
    #pragma unroll
    for (int it = 0; it < 2; ++it)
        #pragma unroll
        for (int fb = 0; fb < 4; ++fb)
            #pragma unroll
            for (int r = 0; r < 4; ++r) {
                int i = i0 + 16 * it + 4 * quad + r;
                int f = 64 * w + 16 * fb + n16;
                size_t a = ((size_t)s * NA + i) * FD + f;
                gbuf[a] = acc[it][fb][r] * gbuf[a];
            }
}

// ---------------------------------------------------------------------------
// Kernel 2 FALLBACK (cooperative, validated round 4) — used if ws < 8 MB.
// ---------------------------------------------------------------------------
__global__ __launch_bounds__(256) void lr_coop(
    const float* __restrict__ pos, float* __restrict__ gbuf)
{
    __shared__ float px[NA], py[NA], pz[NA];
    __shared__ __attribute__((aligned(16))) short svb[64 * 40];
    __shared__ __attribute__((aligned(16))) short sqb[FD * 40];

    const int blk = blockIdx.x;
    const int s   = blk & 31;
    const int i0  = (blk >> 5) * 64;
    const int t   = threadIdx.x;
    const int w    = t >> 6;
    const int lane = t & 63;
    const int n16  = lane & 15;
    const int quad = lane >> 4;

    for (int m = t; m < NA; m += 256) {
        const float* p = &pos[((size_t)s * NA + m) * 3];
        px[m] = p[0]; py[m] = p[1]; pz[m] = p[2];
    }

    f32x4 acc[4][4];
    #pragma unroll
    for (int a = 0; a < 4; ++a)
        #pragma unroll
        for (int c = 0; c < 4; ++c) acc[a][c] = (f32x4)0.0f;

    __syncthreads();

    const int fq  = t >> 2;
    const int jb  = t & 3;
    const int iv  = t & 63;
    const int jbv = t >> 6;
    const int gi  = i0 + iv;

    float4 rq[8];
    #pragma unroll
    for (int m = 0; m < 8; ++m)
        rq[m] = *(const float4*)&gbuf[((size_t)s * NA + 8 * jb + m) * FD + 4 * fq];

    for (int j0 = 0; j0 < NA; j0 += 32) {
        bf16x8 vrow;
        #pragma unroll
        for (int jj = 0; jj < 8; ++jj) {
            int gj = j0 + 8 * jbv + jj;
            float dx = px[gi] - px[gj];
            float dy = py[gi] - py[gj];
            float dz = pz[gi] - pz[gj];
            float dd = sqrtf(dx * dx + dy * dy + dz * dz);
            float om = (dd < 5.0f) ? 0.5f * (1.0f - __cosf(dd * 0.62831853071795f))
                                   : 1.0f;
            float vv = (gi != gj) ? (0.5f * om * __builtin_amdgcn_rcpf(dd)) : 0.0f;
            vrow[jj] = f2bf(vv);
        }
        bf16x8 rows[4];
        #pragma unroll
        for (int m = 0; m < 8; ++m) {
            rows[0][m] = f2bf(rq[m].x);
            rows[1][m] = f2bf(rq[m].y);
            rows[2][m] = f2bf(rq[m].z);
            rows[3][m] = f2bf(rq[m].w);
        }
        #pragma unroll
        for (int d = 0; d < 4; ++d) {
            int f = 4 * fq + d;
            int phys = (jb + (f >> 3)) & 3;
            *(bf16x8*)&sqb[f * 40 + phys * 8] = rows[d];
        }
        {
            int phys = (jbv + (iv >> 3)) & 3;
            *(bf16x8*)&svb[iv * 40 + phys * 8] = vrow;
        }
        {
            int jn = (j0 + 32) & (NA - 1);
            #pragma unroll
            for (int m = 0; m < 8; ++m)
                rq[m] = *(const float4*)&gbuf[((size_t)s * NA + jn + 8 * jb + m) * FD + 4 * fq];
        }
        __syncthreads();

        bf16x8 af[4], bfr[4];
        #pragma unroll
        for (int it = 0; it < 4; ++it) {
            int i = 16 * it + n16;
            int phys = (quad + (i >> 3)) & 3;
            af[it] = *(const bf16x8*)&svb[i * 40 + phys * 8];
        }
        #pragma unroll
        for (int fb = 0; fb < 4; ++fb) {
            int f = 16 * (4 * w + fb) + n16;
            int phys = (quad + (f >> 3)) & 3;
            bfr[fb] = *(const bf16x8*)&sqb[f * 40 + phys * 8];
        }
        #pragma unroll
        for (int it = 0; it < 4; ++it)
            #pragma unroll
            for (int fb = 0; fb < 4; ++fb)
                acc[it][fb] = __builtin_amdgcn_mfma_f32_16x16x32_bf16(
                    af[it], bfr[fb], acc[it][fb], 0, 0, 0);
        __syncthreads();
    }

    cooperative_groups::this_grid().sync();

    #pragma unroll
    for (int it = 0; it < 4; ++it)
        #pragma unroll
        for (int fb = 0; fb < 4; ++fb)
            #pragma unroll
            for (int r = 0; r < 4; ++r) {
                int i = i0 + 16 * it + 4 * quad + r;
                int f = 16 * (4 * w + fb) + n16;
                size_t a = ((size_t)s * NA + i) * FD + f;
                gbuf[a] = acc[it][fb][r] * gbuf[a];
            }
}

extern "C" void kernel_launch(void* const* d_in, const int* in_sizes, int n_in,
                              void* d_out, int out_size, void* d_ws, size_t ws_size,
                              hipStream_t stream) {
    const float* positions = (const float*)d_in[0];  // [32,512,3]
    const float* features  = (const float*)d_in[1];  // [16384,256]
    const float* W         = (const float*)d_in[2];  // [256,256]
    const float* b         = (const float*)d_in[3];  // [256]
    float* gbuf = (float*)d_out;                     // q fp32, then out (in place)

    const size_t qT_bytes = (size_t)SY * NA * FD * sizeof(short);  // 8 MB
    const bool fast = (ws_size >= qT_bytes);
    short* qT = fast ? (short*)d_ws : nullptr;

    charges_mfma<<<dim3(256), 256, 0, stream>>>(features, W, b, gbuf, qT);

    if (fast) {
        lr_fast<<<dim3(512), 256, 0, stream>>>(positions, gbuf, qT);
    } else {
        void* args[] = {(void*)&positions, (void*)&gbuf};
        hipLaunchCooperativeKernel((void*)lr_coop, dim3(256), dim3(256),
                                   args, 0, stream);
    }
}

// Round 6
// 110.190 us; speedup vs baseline: 1.7385x; 1.2297x over previous
//
#include <hip/hip_runtime.h>
#include <hip/hip_cooperative_groups.h>

// S=32 systems, N=512 atoms/system, F=256 features
#define SY 32
#define NA 512
#define FD 256

typedef __attribute__((ext_vector_type(8))) short bf16x8;   // 8 bf16 = 4 VGPRs
typedef __attribute__((ext_vector_type(4))) short bf16x4;   // 4 bf16 = 8 B
typedef __attribute__((ext_vector_type(4))) float f32x4;    // MFMA C/D frag

static __device__ __forceinline__ short f2bf(float x) {
    union { float f; unsigned u; } v; v.f = x;
    unsigned r = v.u + 0x7fffu + ((v.u >> 16) & 1u);   // RNE
    return (short)(r >> 16);
}
static __device__ __forceinline__ float bf2f(short x) {
    union { float f; unsigned u; } v;
    v.u = ((unsigned)(unsigned short)x) << 16;
    return v.f;
}

// ---------------------------------------------------------------------------
// Kernel 1 v2: charges = features @ W^T + b via bf16 MFMA (fp32 accum).
// 256 blocks x 512 threads (8 waves/CU): wave w owns f in [32w,32w+32).
// Fast path: writes ONLY qT bf16 [s][f][j] (coalesced via LDS transpose).
// Fallback path (qfp != nullptr): also writes fp32 q for lr_coop.
// ---------------------------------------------------------------------------
__global__ __launch_bounds__(512) void charges_mfma(
    const float* __restrict__ feat, const float* __restrict__ W,
    const float* __restrict__ b, float* __restrict__ qfp,
    short* __restrict__ qT)
{
    __shared__ __attribute__((aligned(16))) short sA[64 * 72];   //  9.2 KB
    __shared__ __attribute__((aligned(16))) short sB[256 * 72];  // 36.9 KB
    __shared__ __attribute__((aligned(16))) short tr[256 * 72];  // 36.9 KB
    const int t    = threadIdx.x;
    const int i0   = blockIdx.x * 64;
    const int w    = t >> 6;            // wave 0..7
    const int lane = t & 63;
    const int n16  = lane & 15;
    const int quad = lane >> 4;

    f32x4 acc[4][2];
    #pragma unroll
    for (int a = 0; a < 4; ++a)
        #pragma unroll
        for (int c = 0; c < 2; ++c) acc[a][c] = (f32x4)0.0f;

    for (int k0 = 0; k0 < FD; k0 += 64) {
        // stage feat tile 64i x 64k (2 float4/thread)
        #pragma unroll
        for (int m = 0; m < 2; ++m) {
            int lin = t + 512 * m;
            int i = lin >> 4, kq = lin & 15;
            float4 v = *(const float4*)&feat[(size_t)(i0 + i) * FD + k0 + 4 * kq];
            bf16x4 p; p[0] = f2bf(v.x); p[1] = f2bf(v.y);
                      p[2] = f2bf(v.z); p[3] = f2bf(v.w);
            *(bf16x4*)&sA[i * 72 + 4 * kq] = p;
        }
        // stage W tile 256f x 64k (8 float4/thread)
        #pragma unroll
        for (int m = 0; m < 8; ++m) {
            int lin = t + 512 * m;
            int f = lin >> 4, kq = lin & 15;
            float4 v = *(const float4*)&W[(size_t)f * FD + k0 + 4 * kq];
            bf16x4 p; p[0] = f2bf(v.x); p[1] = f2bf(v.y);
                      p[2] = f2bf(v.z); p[3] = f2bf(v.w);
            *(bf16x4*)&sB[f * 72 + 4 * kq] = p;
        }
        __syncthreads();

        #pragma unroll
        for (int ks = 0; ks < 64; ks += 32) {
            bf16x8 af[4], bfr[2];
            #pragma unroll
            for (int it = 0; it < 4; ++it)
                af[it] = *(const bf16x8*)&sA[(16 * it + n16) * 72 + ks + quad * 8];
            #pragma unroll
            for (int fb = 0; fb < 2; ++fb)
                bfr[fb] = *(const bf16x8*)&sB[(32 * w + 16 * fb + n16) * 72 + ks + quad * 8];
            #pragma unroll
            for (int it = 0; it < 4; ++it)
                #pragma unroll
                for (int fb = 0; fb < 2; ++fb)
                    acc[it][fb] = __builtin_amdgcn_mfma_f32_16x16x32_bf16(
                        af[it], bfr[fb], acc[it][fb], 0, 0, 0);
        }
        __syncthreads();
    }

    float bias[2];
    #pragma unroll
    for (int fb = 0; fb < 2; ++fb) bias[fb] = b[32 * w + 16 * fb + n16];

    if (qfp) {   // fallback path needs fp32 q
        #pragma unroll
        for (int it = 0; it < 4; ++it)
            #pragma unroll
            for (int fb = 0; fb < 2; ++fb)
                #pragma unroll
                for (int r = 0; r < 4; ++r) {
                    int i = i0 + 16 * it + 4 * quad + r;
                    int f = 32 * w + 16 * fb + n16;
                    qfp[(size_t)i * FD + f] = acc[it][fb][r] + bias[fb];
                }
    }

    // transpose to [f][i] bf16 in LDS, then coalesced 16B stores to qT
    #pragma unroll
    for (int it = 0; it < 4; ++it)
        #pragma unroll
        for (int fb = 0; fb < 2; ++fb) {
            bf16x4 p;
            #pragma unroll
            for (int r = 0; r < 4; ++r) p[r] = f2bf(acc[it][fb][r] + bias[fb]);
            int f = 32 * w + 16 * fb + n16;
            *(bf16x4*)&tr[f * 72 + 16 * it + 4 * quad] = p;
        }
    __syncthreads();
    {
        short* qTs = qT + ((size_t)(i0 >> 9)) * FD * NA;
        const int ilb = i0 & 511;
        #pragma unroll
        for (int n = 0; n < 4; ++n) {
            int S = n * 512 + t;        // 0..2047
            int f = S >> 3;
            int c = S & 7;
            uint4 v = *(const uint4*)&tr[f * 72 + c * 8];
            *(uint4*)&qTs[(size_t)f * NA + ilb + c * 8] = v;
        }
    }
}

// ---------------------------------------------------------------------------
// Kernel 2 FAST (non-coop): V = 0.5 * v @ q (bf16 MFMA), out = V * q.
// Grid 512 = (s = b&31 [XCD-local], ichunk = b>>5 of 32 rows); 2 blocks/CU.
// Own-tile q snapshot from LDS during the matching j-iteration -> epilogue
// is a pure store (no global q re-read).
// ---------------------------------------------------------------------------
__global__ __launch_bounds__(256) void lr_fast(
    const float* __restrict__ pos, float* __restrict__ gbuf,
    const short* __restrict__ qT)
{
    __shared__ float px[NA], py[NA], pz[NA];
    __shared__ __attribute__((aligned(16))) short sqb[FD * 64];  // 32 KB [f][64j swz]
    __shared__ __attribute__((aligned(16))) short svb[32 * 64];  //  4 KB [i][64j swz]

    const int blk = blockIdx.x;
    const int s   = blk & 31;
    const int i0  = (blk >> 5) * 32;
    const int t   = threadIdx.x;
    const int w    = t >> 6;
    const int lane = t & 63;
    const int n16  = lane & 15;
    const int quad = lane >> 4;

    for (int m = t; m < NA; m += 256) {
        const float* p = &pos[((size_t)s * NA + m) * 3];
        px[m] = p[0]; py[m] = p[1]; pz[m] = p[2];
    }

    f32x4 acc[2][4];
    #pragma unroll
    for (int a = 0; a < 2; ++a)
        #pragma unroll
        for (int c = 0; c < 4; ++c) acc[a][c] = (f32x4)0.0f;
    float qreg[2][4][4];

    const short* qTs = qT + (size_t)s * FD * NA;
    const int pi = t & 31;        // pair-tile i
    const int pc = t >> 5;        // pair-tile j-chunk 0..7
    const int gi = i0 + pi;

    __syncthreads();
    const float xi = px[gi], yi = py[gi], zi = pz[gi];

    for (int j0 = 0; j0 < NA; j0 += 64) {
        // ---- stage q tile: 256f x 64j bf16, 8 x 16B chunks per thread ----
        #pragma unroll
        for (int n = 0; n < 8; ++n) {
            int S  = n * 256 + t;        // 0..2047
            int f  = S >> 3;
            int cs = S & 7;              // LDS slot
            int c  = (cs - f) & 7;       // source chunk
            uint4 v = *(const uint4*)&qTs[(size_t)f * NA + j0 + c * 8];
            *(uint4*)&sqb[f * 64 + cs * 8] = v;
        }
        // ---- v tile: 32i x 64j ----
        bf16x8 vrow;
        #pragma unroll
        for (int jj = 0; jj < 8; ++jj) {
            int gj = j0 + pc * 8 + jj;
            float dx = xi - px[gj];
            float dy = yi - py[gj];
            float dz = zi - pz[gj];
            float r2 = dx * dx + dy * dy + dz * dz;
            float inv = __builtin_amdgcn_rsqf(r2);
            float dd  = r2 * inv;
            // 1 - fcut = sin^2(pi*d/10) for d<5, else 1; 0.5 energy factor
            float sn = __sinf(dd * 0.31415926535f);
            float om = (dd < 5.0f) ? sn * sn : 1.0f;
            float vv = (gi != gj) ? 0.5f * om * inv : 0.0f;
            vrow[jj] = f2bf(vv);
        }
        *(bf16x8*)&svb[pi * 64 + (((pc + pi) & 7) * 8)] = vrow;
        __syncthreads();

        // ---- own-tile q snapshot (once; uniform branch) ----
        if (j0 == (i0 & ~63)) {
            const int jb0 = i0 & 63;     // 0 or 32
            #pragma unroll
            for (int it = 0; it < 2; ++it)
                #pragma unroll
                for (int fb = 0; fb < 4; ++fb) {
                    int f = 64 * w + 16 * fb + n16;
                    #pragma unroll
                    for (int r = 0; r < 4; ++r) {
                        int jl = jb0 + 16 * it + 4 * quad + r;
                        int c  = jl >> 3, o = jl & 7;
                        qreg[it][fb][r] =
                            bf2f(sqb[f * 64 + (((c + f) & 7) * 8) + o]);
                    }
                }
        }

        // ---- fragments + MFMA: 2 it x 4 fb x 2 kh = 16 mfma / wave ----
        bf16x8 af[2][2], bfr[2][4];
        #pragma unroll
        for (int it = 0; it < 2; ++it)
            #pragma unroll
            for (int kh = 0; kh < 2; ++kh) {
                int i = 16 * it + n16;
                int c = kh * 4 + quad;
                af[it][kh] = *(const bf16x8*)&svb[i * 64 + (((c + i) & 7) * 8)];
            }
        #pragma unroll
        for (int fb = 0; fb < 4; ++fb)
            #pragma unroll
            for (int kh = 0; kh < 2; ++kh) {
                int f = 64 * w + 16 * fb + n16;
                int c = kh * 4 + quad;
                bfr[kh][fb] = *(const bf16x8*)&sqb[f * 64 + (((c + f) & 7) * 8)];
            }
        #pragma unroll
        for (int kh = 0; kh < 2; ++kh)
            #pragma unroll
            for (int it = 0; it < 2; ++it)
                #pragma unroll
                for (int fb = 0; fb < 4; ++fb)
                    acc[it][fb] = __builtin_amdgcn_mfma_f32_16x16x32_bf16(
                        af[it][kh], bfr[kh][fb], acc[it][fb], 0, 0, 0);
        __syncthreads();
    }

    // epilogue: out = V * q  (pure store, q from registers)
    #pragma unroll
    for (int it = 0; it < 2; ++it)
        #pragma unroll
        for (int fb = 0; fb < 4; ++fb)
            #pragma unroll
            for (int r = 0; r < 4; ++r) {
                int i = i0 + 16 * it + 4 * quad + r;
                int f = 64 * w + 16 * fb + n16;
                size_t a = ((size_t)s * NA + i) * FD + f;
                gbuf[a] = acc[it][fb][r] * qreg[it][fb][r];
            }
}

// ---------------------------------------------------------------------------
// Kernel 2 FALLBACK (cooperative, validated round 4) — used if ws < 8 MB.
// ---------------------------------------------------------------------------
__global__ __launch_bounds__(256) void lr_coop(
    const float* __restrict__ pos, float* __restrict__ gbuf)
{
    __shared__ float px[NA], py[NA], pz[NA];
    __shared__ __attribute__((aligned(16))) short svb[64 * 40];
    __shared__ __attribute__((aligned(16))) short sqb[FD * 40];

    const int blk = blockIdx.x;
    const int s   = blk & 31;
    const int i0  = (blk >> 5) * 64;
    const int t   = threadIdx.x;
    const int w    = t >> 6;
    const int lane = t & 63;
    const int n16  = lane & 15;
    const int quad = lane >> 4;

    for (int m = t; m < NA; m += 256) {
        const float* p = &pos[((size_t)s * NA + m) * 3];
        px[m] = p[0]; py[m] = p[1]; pz[m] = p[2];
    }

    f32x4 acc[4][4];
    #pragma unroll
    for (int a = 0; a < 4; ++a)
        #pragma unroll
        for (int c = 0; c < 4; ++c) acc[a][c] = (f32x4)0.0f;

    __syncthreads();

    const int fq  = t >> 2;
    const int jb  = t & 3;
    const int iv  = t & 63;
    const int jbv = t >> 6;
    const int gi  = i0 + iv;

    float4 rq[8];
    #pragma unroll
    for (int m = 0; m < 8; ++m)
        rq[m] = *(const float4*)&gbuf[((size_t)s * NA + 8 * jb + m) * FD + 4 * fq];

    for (int j0 = 0; j0 < NA; j0 += 32) {
        bf16x8 vrow;
        #pragma unroll
        for (int jj = 0; jj < 8; ++jj) {
            int gj = j0 + 8 * jbv + jj;
            float dx = px[gi] - px[gj];
            float dy = py[gi] - py[gj];
            float dz = pz[gi] - pz[gj];
            float dd = sqrtf(dx * dx + dy * dy + dz * dz);
            float om = (dd < 5.0f) ? 0.5f * (1.0f - __cosf(dd * 0.62831853071795f))
                                   : 1.0f;
            float vv = (gi != gj) ? (0.5f * om * __builtin_amdgcn_rcpf(dd)) : 0.0f;
            vrow[jj] = f2bf(vv);
        }
        bf16x8 rows[4];
        #pragma unroll
        for (int m = 0; m < 8; ++m) {
            rows[0][m] = f2bf(rq[m].x);
            rows[1][m] = f2bf(rq[m].y);
            rows[2][m] = f2bf(rq[m].z);
            rows[3][m] = f2bf(rq[m].w);
        }
        #pragma unroll
        for (int d = 0; d < 4; ++d) {
            int f = 4 * fq + d;
            int phys = (jb + (f >> 3)) & 3;
            *(bf16x8*)&sqb[f * 40 + phys * 8] = rows[d];
        }
        {
            int phys = (jbv + (iv >> 3)) & 3;
            *(bf16x8*)&svb[iv * 40 + phys * 8] = vrow;
        }
        {
            int jn = (j0 + 32) & (NA - 1);
            #pragma unroll
            for (int m = 0; m < 8; ++m)
                rq[m] = *(const float4*)&gbuf[((size_t)s * NA + jn + 8 * jb + m) * FD + 4 * fq];
        }
        __syncthreads();

        bf16x8 af[4], bfr[4];
        #pragma unroll
        for (int it = 0; it < 4; ++it) {
            int i = 16 * it + n16;
            int phys = (quad + (i >> 3)) & 3;
            af[it] = *(const bf16x8*)&svb[i * 40 + phys * 8];
        }
        #pragma unroll
        for (int fb = 0; fb < 4; ++fb) {
            int f = 16 * (4 * w + fb) + n16;
            int phys = (quad + (f >> 3)) & 3;
            bfr[fb] = *(const bf16x8*)&sqb[f * 40 + phys * 8];
        }
        #pragma unroll
        for (int it = 0; it < 4; ++it)
            #pragma unroll
            for (int fb = 0; fb < 4; ++fb)
                acc[it][fb] = __builtin_amdgcn_mfma_f32_16x16x32_bf16(
                    af[it], bfr[fb], acc[it][fb], 0, 0, 0);
        __syncthreads();
    }

    cooperative_groups::this_grid().sync();

    #pragma unroll
    for (int it = 0; it < 4; ++it)
        #pragma unroll
        for (int fb = 0; fb < 4; ++fb)
            #pragma unroll
            for (int r = 0; r < 4; ++r) {
                int i = i0 + 16 * it + 4 * quad + r;
                int f = 16 * (4 * w + fb) + n16;
                size_t a = ((size_t)s * NA + i) * FD + f;
                gbuf[a] = acc[it][fb][r] * gbuf[a];
            }
}

extern "C" void kernel_launch(void* const* d_in, const int* in_sizes, int n_in,
                              void* d_out, int out_size, void* d_ws, size_t ws_size,
                              hipStream_t stream) {
    const float* positions = (const float*)d_in[0];  // [32,512,3]
    const float* features  = (const float*)d_in[1];  // [16384,256]
    const float* W         = (const float*)d_in[2];  // [256,256]
    const float* b         = (const float*)d_in[3];  // [256]
    float* gbuf = (float*)d_out;

    const size_t qT_bytes = (size_t)SY * NA * FD * sizeof(short);  // 8 MB
    const bool fast = (ws_size >= qT_bytes);
    short* qT = fast ? (short*)d_ws : nullptr;

    if (fast) {
        charges_mfma<<<dim3(256), 512, 0, stream>>>(features, W, b, nullptr, qT);
        lr_fast<<<dim3(512), 256, 0, stream>>>(positions, gbuf, qT);
    } else {
        // fallback: q fp32 in d_out, cooperative in-place update
        charges_mfma<<<dim3(256), 512, 0, stream>>>(features, W, b, gbuf,
                                                    (short*)d_out /*unused-safe*/);
        void* args[] = {(void*)&positions, (void*)&gbuf};
        hipLaunchCooperativeKernel((void*)lr_coop, dim3(256), dim3(256),
                                   args, 0, stream);
    }
}